// Round 6
// baseline (994.101 us; speedup 1.0000x reference)
//
#include <hip/hip_runtime.h>
#include <hip/hip_fp16.h>

constexpr int NN   = 100000;
constexpr int NE   = 3200000;
constexpr int FIN  = 512;
constexpr int FH   = 16;
constexpr int FOUT = 64;

constexpr int BSH = 6;                     // bucket shift (64 nodes/bucket)
constexpr int BSZ = 64;
constexpr int K   = (NN + BSZ - 1) / BSZ;  // 1563 buckets
constexpr int NB  = 512;                   // binning blocks
constexpr int CHUNK = NE / NB;             // 6250 edges per block (exact)
constexpr int AP  = 17;                    // padded LDS accumulator row (bank spread)

// per-block bucket counts: M[k*NB + b]
__global__ __launch_bounds__(256) void k_cnt(const int* __restrict__ ei, int* __restrict__ M) {
    __shared__ int h[K];
    int t = threadIdx.x, b = blockIdx.x;
    for (int i = t; i < K; i += 256) h[i] = 0;
    __syncthreads();
    int e0 = b * CHUNK;
    for (int e = e0 + t; e < e0 + CHUNK; e += 256)
        atomicAdd(&h[ei[NE + e] >> BSH], 1);
    __syncthreads();
    for (int i = t; i < K; i += 256) M[i * NB + b] = h[i];
}

// per bucket-row exclusive scan over the NB blocks, in place; bucket totals out.
__global__ __launch_bounds__(256) void k_scanM(int* __restrict__ M, int* __restrict__ btot) {
    int k = blockIdx.x, t = threadIdx.x;
    int2* row = (int2*)(M + (size_t)k * NB);
    int2 v = row[t];                       // 256 threads x 2 = NB
    int s = v.x + v.y;
    int lane = t & 63, wid = t >> 6;
    int ps = s;
    #pragma unroll
    for (int off = 1; off < 64; off <<= 1) {
        int u = __shfl_up(ps, off, 64);
        if (lane >= off) ps += u;
    }
    __shared__ int wsum[4];
    if (lane == 63) wsum[wid] = ps;
    __syncthreads();
    int base = 0;
    for (int w = 0; w < wid; ++w) base += wsum[w];
    int excl = base + ps - s;
    int2 o; o.x = excl; o.y = excl + v.x;
    row[t] = o;
    if (t == 255) btot[k] = excl + s;
}

// exclusive scan of bucket totals (K=1563) -> bstart[K+1]; 2 elems/thread
__global__ __launch_bounds__(1024) void k_scanB(const int* __restrict__ btot, int* __restrict__ bstart) {
    int t = threadIdx.x;
    int i0 = 2 * t, i1 = 2 * t + 1;
    int c0 = (i0 < K) ? btot[i0] : 0;
    int c1 = (i1 < K) ? btot[i1] : 0;
    int s = c0 + c1;
    int lane = t & 63, wid = t >> 6;
    int ps = s;
    #pragma unroll
    for (int off = 1; off < 64; off <<= 1) {
        int u = __shfl_up(ps, off, 64);
        if (lane >= off) ps += u;
    }
    __shared__ int wsum[16];
    if (lane == 63) wsum[wid] = ps;
    __syncthreads();
    int base = 0;
    for (int w = 0; w < wid; ++w) base += wsum[w];
    int excl = base + ps - s;
    if (i0 < K) bstart[i0] = excl;
    if (i1 < K) bstart[i1] = excl + c0;
    if (t == 0) bstart[K] = NE;
}

// deterministic scatter: rec[pos] = (src<<6) | d_local, positions from scans (LDS cursors only)
__global__ __launch_bounds__(256) void k_scatter2(const int* __restrict__ ei,
                                                  const int* __restrict__ M,
                                                  const int* __restrict__ bstart,
                                                  int* __restrict__ rec) {
    __shared__ int cur[K];
    int t = threadIdx.x, b = blockIdx.x;
    for (int i = t; i < K; i += 256) cur[i] = bstart[i] + M[i * NB + b];
    __syncthreads();
    int e0 = b * CHUNK;
    for (int e = e0 + t; e < e0 + CHUNK; e += 256) {
        int s = ei[e];
        int d = ei[NE + e];
        int pos = atomicAdd(&cur[d >> BSH], 1);
        rec[pos] = (s << BSH) | (d & (BSZ - 1));
    }
}

// per-bucket degree histogram -> dis = rsqrt(deg+1)
__global__ __launch_bounds__(256) void k_deg_dis(const int* __restrict__ rec,
                                                 const int* __restrict__ bstart,
                                                 float* __restrict__ dis) {
    __shared__ int h[BSZ];
    int t = threadIdx.x, k = blockIdx.x;
    if (t < BSZ) h[t] = 0;
    __syncthreads();
    int e0 = bstart[k], e1 = bstart[k + 1];
    for (int e = e0 + t; e < e1; e += 256)
        atomicAdd(&h[rec[e] & (BSZ - 1)], 1);
    __syncthreads();
    if (t < BSZ) {
        int node = k * BSZ + t;
        if (node < NN) dis[node] = rsqrtf((float)h[t] + 1.0f);
    }
}

// vp1h = fp16( dis * (x @ W1) )   [NN,512]x[512,16] -> [NN,16] half
__global__ __launch_bounds__(256) void k_gemm1(const float* __restrict__ x,
                                               const float* __restrict__ W1,
                                               const float* __restrict__ dis,
                                               __half* __restrict__ vp1h) {
    __shared__ float ws[128 * FH];
    __shared__ float xs[64 * 132];
    int t = threadIdx.x;
    int row0 = blockIdx.x * 64;
    int r  = t >> 2;
    int jb = (t & 3) * 4;
    float acc0 = 0.f, acc1 = 0.f, acc2 = 0.f, acc3 = 0.f;

    for (int kc = 0; kc < 4; ++kc) {
        __syncthreads();
        {
            const float* wsrc = &W1[kc * 128 * FH];
            *(float4*)&ws[t * 4]        = *(const float4*)&wsrc[t * 4];
            *(float4*)&ws[1024 + t * 4] = *(const float4*)&wsrc[1024 + t * 4];
        }
        for (int it = 0; it < 8; ++it) {
            int idx = it * 1024 + t * 4;
            int rr = idx >> 7;
            int cc = idx & 127;
            int gr = row0 + rr; if (gr >= NN) gr = NN - 1;
            *(float4*)&xs[rr * 132 + cc] = *(const float4*)&x[(size_t)gr * FIN + kc * 128 + cc];
        }
        __syncthreads();
        const float* xrow = &xs[r * 132];
        #pragma unroll 8
        for (int k = 0; k < 128; ++k) {
            float xv = xrow[k];
            float4 w = *(const float4*)&ws[k * FH + jb];
            acc0 += xv * w.x; acc1 += xv * w.y; acc2 += xv * w.z; acc3 += xv * w.w;
        }
    }
    int node = row0 + r;
    if (node < NN) {
        float d = dis[node];
        union { __half2 h2[2]; uint2 u; } pk;
        pk.h2[0] = __floats2half2_rn(d * acc0, d * acc1);
        pk.h2[1] = __floats2half2_rn(d * acc2, d * acc3);
        *(uint2*)&vp1h[node * FH + jb] = pk.u;
    }
}

// one edge: gather 4 halves (8B) from vph row, accumulate into padded LDS row
__device__ __forceinline__ void edge_accum(int r, const __half* __restrict__ vph,
                                           float* __restrict__ acc, int q) {
    union { uint2 u; __half2 h2[2]; } g;
    g.u = *(const uint2*)&vph[(r >> BSH) * FH + q * 4];
    float2 a = __half22float2(g.h2[0]);
    float2 b = __half22float2(g.h2[1]);
    float* ap = &acc[(r & (BSZ - 1)) * AP + q * 4];
    atomicAdd(ap + 0, a.x); atomicAdd(ap + 1, a.y);
    atomicAdd(ap + 2, b.x); atomicAdd(ap + 3, b.y);
}

// edge loop: 4 lanes/edge, 4-way unroll (64 edges in flight per wave)
__device__ __forceinline__ void agg_edges_h(const int* __restrict__ rec, int e0, int e1,
                                            const __half* __restrict__ vph,
                                            float* __restrict__ acc, int slot, int q) {
    int e = e0 + slot;
    for (; e + 3 * BSZ < e1; e += 4 * BSZ) {
        int r0 = rec[e];
        int r1 = rec[e + BSZ];
        int r2 = rec[e + 2 * BSZ];
        int r3 = rec[e + 3 * BSZ];
        edge_accum(r0, vph, acc, q);
        edge_accum(r1, vph, acc, q);
        edge_accum(r2, vph, acc, q);
        edge_accum(r3, vph, acc, q);
    }
    for (; e < e1; e += BSZ)
        edge_accum(rec[e], vph, acc, q);
}

// layer-1 aggregate + bias + relu + pre-scale -> vp2h (fp16)
__global__ __launch_bounds__(256) void k_agg1(const int* __restrict__ rec,
                                              const int* __restrict__ bstart,
                                              const float* __restrict__ dis,
                                              const __half* __restrict__ vp1h,
                                              const float* __restrict__ b1,
                                              __half* __restrict__ vp2h) {
    __shared__ float acc[BSZ * AP];   // 4.25 KB
    int t = threadIdx.x, k = blockIdx.x;
    for (int i = t; i < BSZ * AP; i += 256) acc[i] = 0.f;
    __syncthreads();
    agg_edges_h(rec, bstart[k], bstart[k + 1], vp1h, acc, t >> 2, t & 3);
    __syncthreads();
    for (int i = t; i < BSZ * FH; i += 256) {
        int n = i >> 4, ff = i & 15;
        int node = k * BSZ + n;
        if (node < NN) {
            float dv = dis[node];
            float self = __half2float(vp1h[node * FH + ff]);
            float h = dv * (acc[n * AP + ff] + self) + b1[ff];
            h = h > 0.f ? h : 0.f;
            vp2h[node * FH + ff] = __float2half_rn(dv * h);
        }
    }
}

// layer-2 aggregate + GEMM2(16->64) + bias + relu
__global__ __launch_bounds__(256) void k_agg2(const int* __restrict__ rec,
                                              const int* __restrict__ bstart,
                                              const float* __restrict__ dis,
                                              const __half* __restrict__ vp2h,
                                              const float* __restrict__ W2,
                                              const float* __restrict__ b2,
                                              float* __restrict__ out) {
    __shared__ float acc[BSZ * AP];   // 4.25 KB
    __shared__ float ws[FH * FOUT];   // 4 KB
    int t = threadIdx.x, k = blockIdx.x;
    *(float4*)&ws[t * 4] = *(const float4*)&W2[t * 4];
    for (int i = t; i < BSZ * AP; i += 256) acc[i] = 0.f;
    __syncthreads();
    agg_edges_h(rec, bstart[k], bstart[k + 1], vp2h, acc, t >> 2, t & 3);
    __syncthreads();
    // finalize a16 in place: a16 = dis[d]*(acc + vp2[d])
    for (int i = t; i < BSZ * FH; i += 256) {
        int n = i >> 4, ff = i & 15;
        int node = k * BSZ + n;
        float dv = (node < NN) ? dis[node] : 0.f;
        float self = (node < NN) ? __half2float(vp2h[node * FH + ff]) : 0.f;
        acc[n * AP + ff] = dv * (acc[n * AP + ff] + self);
    }
    __syncthreads();
    // GEMM: 4 nodes per pass x 64 output lanes
    int j = t & 63;
    float bj = b2[j];
    for (int n = t >> 6; n < BSZ; n += 4) {
        int node = k * BSZ + n;
        if (node >= NN) break;
        float s = 0.f;
        #pragma unroll
        for (int kk = 0; kk < FH; ++kk)
            s += acc[n * AP + kk] * ws[kk * FOUT + j];
        out[node * FOUT + j] = fmaxf(s + bj, 0.f);
    }
}

extern "C" void kernel_launch(void* const* d_in, const int* in_sizes, int n_in,
                              void* d_out, int out_size, void* d_ws, size_t ws_size,
                              hipStream_t stream) {
    const float* x  = (const float*)d_in[0];
    const int*   ei = (const int*)d_in[1];
    const float* W1 = (const float*)d_in[2];
    const float* b1 = (const float*)d_in[3];
    const float* W2 = (const float*)d_in[4];
    const float* b2 = (const float*)d_in[5];
    float* out = (float*)d_out;

    // workspace (~24 MB)
    char* p = (char*)d_ws;
    int*    M      = (int*)p;     p += (size_t)K * NB * 4;       // 3.2 MB
    int*    btot   = (int*)p;     p += 2048 * 4;
    int*    bstart = (int*)p;     p += 2048 * 4;
    int*    rec    = (int*)p;     p += (size_t)NE * 4;           // 12.8 MB
    float*  dis    = (float*)p;   p += 100032 * 4;
    __half* vp1h   = (__half*)p;  p += (size_t)NN * FH * 2;      // 3.2 MB
    __half* vp2h   = (__half*)p;                                 // 3.2 MB

    k_cnt     <<<NB, 256, 0, stream>>>(ei, M);
    k_scanM   <<<K, 256, 0, stream>>>(M, btot);
    k_scanB   <<<1, 1024, 0, stream>>>(btot, bstart);
    k_scatter2<<<NB, 256, 0, stream>>>(ei, M, bstart, rec);
    k_deg_dis <<<K, 256, 0, stream>>>(rec, bstart, dis);

    k_gemm1   <<<(NN + 63) / 64, 256, 0, stream>>>(x, W1, dis, vp1h);
    k_agg1    <<<K, 256, 0, stream>>>(rec, bstart, dis, vp1h, b1, vp2h);
    k_agg2    <<<K, 256, 0, stream>>>(rec, bstart, dis, vp2h, W2, b2, out);
}